// Round 14
// baseline (66.018 us; speedup 1.0000x reference)
//
#include <hip/hip_runtime.h>
#include <hip/hip_bf16.h>

#define ALPHA 0.2f
#define LOG2E 1.4426950408889634f

typedef __attribute__((ext_vector_type(8))) short bf16x8;
typedef __attribute__((ext_vector_type(4))) float f32x4;
typedef __attribute__((ext_vector_type(4))) int i32x4;

__device__ __forceinline__ int cvt_pk_bf16(float lo, float hi) {
    int r;
    asm("v_cvt_pk_bf16_f32 %0, %1, %2" : "=v"(r) : "v"(lo), "v"(hi));
    return r;
}

// async global->LDS, 16B per lane; LDS dest = wave-uniform base + lane*16
__device__ __forceinline__ void stage16(const void* g, void* l) {
    __builtin_amdgcn_global_load_lds(
        (const __attribute__((address_space(1))) void*)g,
        (__attribute__((address_space(3))) void*)l, 16, 0, 0);
}

// ordered-uint encoding for float atomicMax (monotone: a<b <=> enc(a)<enc(b));
// memset-0 init always loses (real keys are >= 0x00800000).
__device__ __forceinline__ unsigned enc_f(float f) {
    unsigned u = __float_as_uint(f);
    return (u & 0x80000000u) ? ~u : (u | 0x80000000u);
}
__device__ __forceinline__ float dec_f(unsigned k) {
    return __uint_as_float((k & 0x80000000u) ? (k & 0x7FFFFFFFu) : ~k);
}

// ---------------------------------------------------------------------------
// Kernel A (verified round-11 + sjmax fold): Wh = h @ W (fp32), si2/sj2
// scaled by log2e, Wh PRE-FRAGMENTED for the MFMA B operand:
//   WhF[((b*64 + jc)*4 + ob)*512 + lane*8 + e] = bf16(Wh[j][o]),
//   j = jc*32 + (lane>>4)*8 + e, o = ob*16 + (lane&15)
// plus sjmax[b] published via ordered-uint atomicMax (1 atomic per wave).
// ---------------------------------------------------------------------------
__global__ __launch_bounds__(256) void gat_precompute(
    const float* __restrict__ h, const float* __restrict__ W,
    const float* __restrict__ a, unsigned short* __restrict__ WhF,
    float* __restrict__ si2, float* __restrict__ sj2,
    unsigned* __restrict__ sjmax_enc)
{
    __shared__ float h_lds[32][128];
    __shared__ float wh_lds[32][65];   // +1 pad
    const int tid  = threadIdx.x;
    const int lane = tid & 63;
    const int wave = tid >> 6;
    const long long row0 = (long long)blockIdx.x * 32;

    {
        const float4* s4 = (const float4*)(h + row0 * 128);
        #pragma unroll
        for (int i = 0; i < 4; ++i) {
            int idx = tid + i * 256;
            float4 v = s4[idx];
            *(float4*)&h_lds[idx >> 5][(idx & 31) * 4] = v;
        }
    }
    __syncthreads();

    const float a1 = a[lane];
    const float a2 = a[64 + lane];
    float acc[8];
    #pragma unroll
    for (int r = 0; r < 8; ++r) acc[r] = 0.0f;

    for (int f = 0; f < 128; f += 4) {
        const float w0 = W[(f+0)*64 + lane];
        const float w1 = W[(f+1)*64 + lane];
        const float w2 = W[(f+2)*64 + lane];
        const float w3 = W[(f+3)*64 + lane];
        #pragma unroll
        for (int r = 0; r < 8; ++r) {
            const float4 hv = *(const float4*)&h_lds[wave*8 + r][f];
            acc[r] = fmaf(hv.x, w0, acc[r]);
            acc[r] = fmaf(hv.y, w1, acc[r]);
            acc[r] = fmaf(hv.z, w2, acc[r]);
            acc[r] = fmaf(hv.w, w3, acc[r]);
        }
    }

    float smax = -INFINITY;                 // block-local sj2 max (all lanes)
    #pragma unroll
    for (int r = 0; r < 8; ++r) {
        const int rr = wave*8 + r;
        wh_lds[rr][lane] = acc[r];
        float s1 = acc[r] * a1;
        float s2 = acc[r] * a2;
        #pragma unroll
        for (int off = 32; off > 0; off >>= 1) {
            s1 += __shfl_xor(s1, off);
            s2 += __shfl_xor(s2, off);
        }
        smax = fmaxf(smax, s2 * LOG2E);     // butterfly left sum in all lanes
        if (lane == 0) {
            si2[row0 + rr] = s1 * LOG2E;
            sj2[row0 + rr] = s2 * LOG2E;
        }
    }
    if (lane == 0)
        atomicMax(sjmax_enc + (row0 >> 11), enc_f(smax));
    __syncthreads();

    // fragment write: tid = ob*64 + lane
    const long long b  = row0 >> 11;
    const int jcb  = (int)((row0 & 2047) >> 5);   // j-chunk within batch
    const int ob   = tid >> 6;
    const int ln   = tid & 63;
    const int ar   = ln & 15;
    const int gg   = ln >> 4;
    i32x4 pk;
    #pragma unroll
    for (int k = 0; k < 4; ++k)
        pk[k] = cvt_pk_bf16(wh_lds[gg*8 + 2*k    ][ob*16 + ar],
                            wh_lds[gg*8 + 2*k + 1][ob*16 + ar]);
    *(i32x4*)(WhF + ((b*64 + jcb)*4 + ob)*512 + ln*8) = pk;
}

// ---------------------------------------------------------------------------
// Kernel B (round-11 minimum, sjmax prologue removed): fused masked-softmax
// attention. Block = (batch b = bid&7 -> XCD affinity, 16-row i-tile); grid
// 1024 -> 4 blocks/CU (LDS 16.6KB). 4 waves = private 512-j quarters, 16
// dbuf steps of 32 j.
//  - adj: global_load_lds staging (2KB/wave/step, swizzle u^(r&7))
//  - Wh:  pre-fragmented global B-fragments, prefetched 1 step ahead in regs
//  - sj:  direct per-lane loads (L1-hot); sjmax: one scalar read
// p = exp2(max(Ci+sj, 0.2*sj+Di)) * (adj>0), fixed row max (lrelu monotone).
// ---------------------------------------------------------------------------
__global__ __launch_bounds__(256, 4) void gat_attention(
    const int* __restrict__ adj, const unsigned short* __restrict__ WhF,
    const float* __restrict__ si2, const float* __restrict__ sj2,
    const unsigned* __restrict__ sjmax_enc, float* __restrict__ out)
{
    __shared__ char ldsbuf[16640];   // 2 x 8KB adj dbuf; epi: accb 16K + lb
    const int tid  = threadIdx.x;
    const int lane = tid & 63;
    const int wave = tid >> 6;
    const int b    = blockIdx.x & 7;                 // batch -> XCD affinity
    const int i0   = (int)((blockIdx.x >> 3) << 4);  // 16-row i-tile
    const int arow = lane & 15;
    const int g    = lane >> 4;
    const long long bN = (long long)b * 2048;

    // ---- adj staging sources (pre-swizzled: slot pu holds unit pu^(r&7)) --
    const int* asrc0;
    const int* asrc1;
    {
        int r = lane >> 3;
        int u = (lane & 7) ^ (r & 7);
        asrc0 = adj + (bN + i0 + r)*2048 + wave*512 + u*4;
        int r2 = 8 + (lane >> 3);
        int u2 = (lane & 7) ^ (r2 & 7);
        asrc1 = adj + (bN + i0 + r2)*2048 + wave*512 + u2*4;
    }

    // ---- B-fragment base: frag (st, ob) at fbase + (st*4 + ob)*512 ----
    const unsigned short* fbase =
        WhF + ((long long)(b*64 + wave*16) * 4) * 512 + lane*8;

    const float mx   = dec_f(sjmax_enc[b]);        // precomputed batch max
    const float si_r = si2[bN + i0 + arow];        // P-row = arow
    const float u0f  = si_r + mx;
    const float m2   = fmaxf(u0f, ALPHA * u0f);    // fixed row max (log2 dom)
    const float Ci   = si_r - m2;
    const float Di   = ALPHA * si_r - m2;

    const float* sjq = sj2 + bN + wave*512 + g*8;  // this lane's sj stream

    f32x4 accf[4];
    #pragma unroll
    for (int ob = 0; ob < 4; ++ob) accf[ob] = (f32x4){0.f,0.f,0.f,0.f};
    f32x4 accl = (f32x4){0.f,0.f,0.f,0.f};
    bf16x8 ones;
    #pragma unroll
    for (int k = 0; k < 8; ++k) ones[k] = (short)0x3F80;   // bf16 1.0

    bf16x8 cb0, cb1, cb2, cb3, nb0, nb1, nb2, nb3;

    #define STAGE(S, STEP) { \
        char* base_ = ldsbuf + (S)*8192 + wave*2048; \
        stage16(asrc0 + (STEP)*32, base_); \
        stage16(asrc1 + (STEP)*32, base_ + 1024); \
    }

    #define LOADB(D0, D1, D2, D3, STEP) { \
        D0 = *(const bf16x8*)(fbase + ((STEP)*4 + 0)*512); \
        D1 = *(const bf16x8*)(fbase + ((STEP)*4 + 1)*512); \
        D2 = *(const bf16x8*)(fbase + ((STEP)*4 + 2)*512); \
        D3 = *(const bf16x8*)(fbase + ((STEP)*4 + 3)*512); \
    }

    #define BODY(S, STEP) { \
        const char* ab = ldsbuf + (S)*8192 + wave*2048; \
        const i32x4 A0 = *(const i32x4*)(ab + arow*128 + ((g*2    ) ^ (arow & 7))*16); \
        const i32x4 A1 = *(const i32x4*)(ab + arow*128 + ((g*2 + 1) ^ (arow & 7))*16); \
        const f32x4 S0 = *(const f32x4*)(sjq + (STEP)*32); \
        const f32x4 S1 = *(const f32x4*)(sjq + (STEP)*32 + 4); \
        float p[8]; \
        _Pragma("unroll") \
        for (int e = 0; e < 4; ++e) { \
            float pe = __builtin_amdgcn_exp2f( \
                fmaxf(Ci + S0[e], fmaf(ALPHA, S0[e], Di))); \
            p[e] = (A0[e] > 0) ? pe : 0.0f; \
        } \
        _Pragma("unroll") \
        for (int e = 0; e < 4; ++e) { \
            float pe = __builtin_amdgcn_exp2f( \
                fmaxf(Ci + S1[e], fmaf(ALPHA, S1[e], Di))); \
            p[4+e] = (A1[e] > 0) ? pe : 0.0f; \
        } \
        i32x4 pk_; \
        pk_[0] = cvt_pk_bf16(p[0], p[1]); \
        pk_[1] = cvt_pk_bf16(p[2], p[3]); \
        pk_[2] = cvt_pk_bf16(p[4], p[5]); \
        pk_[3] = cvt_pk_bf16(p[6], p[7]); \
        const bf16x8 pa = __builtin_bit_cast(bf16x8, pk_); \
        accl    = __builtin_amdgcn_mfma_f32_16x16x32_bf16(pa, ones, accl,    0, 0, 0); \
        accf[0] = __builtin_amdgcn_mfma_f32_16x16x32_bf16(pa, cb0, accf[0], 0, 0, 0); \
        accf[1] = __builtin_amdgcn_mfma_f32_16x16x32_bf16(pa, cb1, accf[1], 0, 0, 0); \
        accf[2] = __builtin_amdgcn_mfma_f32_16x16x32_bf16(pa, cb2, accf[2], 0, 0, 0); \
        accf[3] = __builtin_amdgcn_mfma_f32_16x16x32_bf16(pa, cb3, accf[3], 0, 0, 0); \
    }

    // ---- prologue ----
    STAGE(0, 0);
    LOADB(cb0, cb1, cb2, cb3, 0);
    __syncthreads();

    // ---- main loop: one barrier/step; B-frags prefetched in regs ----
    int s = 0;
    for (int st = 0; st < 15; ++st) {
        STAGE(s^1, st+1);
        LOADB(nb0, nb1, nb2, nb3, st+1);
        BODY(s, st);
        __syncthreads();
        cb0 = nb0; cb1 = nb1; cb2 = nb2; cb3 = nb3;
        s ^= 1;
    }
    BODY(s, 15);

    // ---- epilogue: combine the 4 j-quarter partials, divide, store ----
    __syncthreads();                          // all waves done with adj bufs
    float* accb = (float*)ldsbuf;             // [4 wave][16 i][64 o] = 16KB
    float* lb   = (float*)(ldsbuf + 16384);   // [4 wave][16 i]
    #pragma unroll
    for (int ob = 0; ob < 4; ++ob)
        #pragma unroll
        for (int reg = 0; reg < 4; ++reg)
            accb[(wave*16 + g*4 + reg)*64 + ob*16 + arow] = accf[ob][reg];
    if (arow == 0) {
        #pragma unroll
        for (int reg = 0; reg < 4; ++reg)
            lb[wave*16 + g*4 + reg] = accl[reg];
    }
    __syncthreads();

    const int r  = tid >> 4;                  // 0..15
    const int c0 = (tid & 15) * 4;
    const float L = lb[r] + lb[16 + r] + lb[32 + r] + lb[48 + r];
    const float inv = 1.0f / L;
    float4 v;
    v.x = (accb[r*64 + c0 + 0] + accb[(16+r)*64 + c0 + 0]
         + accb[(32+r)*64 + c0 + 0] + accb[(48+r)*64 + c0 + 0]) * inv;
    v.y = (accb[r*64 + c0 + 1] + accb[(16+r)*64 + c0 + 1]
         + accb[(32+r)*64 + c0 + 1] + accb[(48+r)*64 + c0 + 1]) * inv;
    v.z = (accb[r*64 + c0 + 2] + accb[(16+r)*64 + c0 + 2]
         + accb[(32+r)*64 + c0 + 2] + accb[(48+r)*64 + c0 + 2]) * inv;
    v.w = (accb[r*64 + c0 + 3] + accb[(16+r)*64 + c0 + 3]
         + accb[(32+r)*64 + c0 + 3] + accb[(48+r)*64 + c0 + 3]) * inv;
    *(float4*)(out + (bN + i0 + r)*64 + c0) = v;
}

// ---------------------------------------------------------------------------
// ws layout: WhF 2MB | si2 64KB | sj2 64KB | sjmax_enc 32B
// ---------------------------------------------------------------------------
extern "C" void kernel_launch(void* const* d_in, const int* in_sizes, int n_in,
                              void* d_out, int out_size, void* d_ws, size_t ws_size,
                              hipStream_t stream) {
    const float* h   = (const float*)d_in[0];
    const int*   adj = (const int*)d_in[1];
    const float* W   = (const float*)d_in[2];
    const float* a   = (const float*)d_in[3];
    float* out = (float*)d_out;

    unsigned short* WhF = (unsigned short*)d_ws;                // 2 MB
    float* si2 = (float*)((char*)d_ws + (size_t)16384*64*2);
    float* sj2 = si2 + 16384;
    unsigned* sjmax_enc = (unsigned*)(sj2 + 16384);             // 8 uints

    hipMemsetAsync(sjmax_enc, 0, 8*sizeof(unsigned), stream);   // det. replays
    gat_precompute<<<512, 256, 0, stream>>>(h, W, a, WhF, si2, sj2, sjmax_enc);
    gat_attention<<<1024, 256, 0, stream>>>(adj, WhF, si2, sj2, sjmax_enc, out);
}

// Round 15
// 45.120 us; speedup vs baseline: 1.4631x; 1.4631x over previous
//
#include <hip/hip_runtime.h>
#include <hip/hip_bf16.h>

#define ALPHA 0.2f
#define LOG2E 1.4426950408889634f

typedef __attribute__((ext_vector_type(8))) short bf16x8;
typedef __attribute__((ext_vector_type(4))) float f32x4;
typedef __attribute__((ext_vector_type(4))) int i32x4;

__device__ __forceinline__ int cvt_pk_bf16(float lo, float hi) {
    int r;
    asm("v_cvt_pk_bf16_f32 %0, %1, %2" : "=v"(r) : "v"(lo), "v"(hi));
    return r;
}

// async global->LDS, 16B per lane; LDS dest = wave-uniform base + lane*16
__device__ __forceinline__ void stage16(const void* g, void* l) {
    __builtin_amdgcn_global_load_lds(
        (const __attribute__((address_space(1))) void*)g,
        (__attribute__((address_space(3))) void*)l, 16, 0, 0);
}

// ---------------------------------------------------------------------------
// Kernel A (verified round-11, unchanged): Wh = h @ W (fp32), si2/sj2 scaled
// by log2e, Wh emitted PRE-FRAGMENTED for the MFMA B operand:
//   WhF[((b*64 + jc)*4 + ob)*512 + lane*8 + e] = bf16(Wh[j][o]),
//   j = jc*32 + (lane>>4)*8 + e, o = ob*16 + (lane&15)
// ---------------------------------------------------------------------------
__global__ __launch_bounds__(256) void gat_precompute(
    const float* __restrict__ h, const float* __restrict__ W,
    const float* __restrict__ a, unsigned short* __restrict__ WhF,
    float* __restrict__ si2, float* __restrict__ sj2)
{
    __shared__ float h_lds[32][128];
    __shared__ float wh_lds[32][65];   // +1 pad
    const int tid  = threadIdx.x;
    const int lane = tid & 63;
    const int wave = tid >> 6;
    const long long row0 = (long long)blockIdx.x * 32;

    {
        const float4* s4 = (const float4*)(h + row0 * 128);
        #pragma unroll
        for (int i = 0; i < 4; ++i) {
            int idx = tid + i * 256;
            float4 v = s4[idx];
            *(float4*)&h_lds[idx >> 5][(idx & 31) * 4] = v;
        }
    }
    __syncthreads();

    const float a1 = a[lane];
    const float a2 = a[64 + lane];
    float acc[8];
    #pragma unroll
    for (int r = 0; r < 8; ++r) acc[r] = 0.0f;

    for (int f = 0; f < 128; f += 4) {
        const float w0 = W[(f+0)*64 + lane];
        const float w1 = W[(f+1)*64 + lane];
        const float w2 = W[(f+2)*64 + lane];
        const float w3 = W[(f+3)*64 + lane];
        #pragma unroll
        for (int r = 0; r < 8; ++r) {
            const float4 hv = *(const float4*)&h_lds[wave*8 + r][f];
            acc[r] = fmaf(hv.x, w0, acc[r]);
            acc[r] = fmaf(hv.y, w1, acc[r]);
            acc[r] = fmaf(hv.z, w2, acc[r]);
            acc[r] = fmaf(hv.w, w3, acc[r]);
        }
    }

    #pragma unroll
    for (int r = 0; r < 8; ++r) {
        const int rr = wave*8 + r;
        wh_lds[rr][lane] = acc[r];
        float s1 = acc[r] * a1;
        float s2 = acc[r] * a2;
        #pragma unroll
        for (int off = 32; off > 0; off >>= 1) {
            s1 += __shfl_xor(s1, off);
            s2 += __shfl_xor(s2, off);
        }
        if (lane == 0) {
            si2[row0 + rr] = s1 * LOG2E;
            sj2[row0 + rr] = s2 * LOG2E;
        }
    }
    __syncthreads();

    // fragment write: tid = ob*64 + lane
    const long long b  = row0 >> 11;
    const int jcb  = (int)((row0 & 2047) >> 5);   // j-chunk within batch
    const int ob   = tid >> 6;
    const int ln   = tid & 63;
    const int ar   = ln & 15;
    const int gg   = ln >> 4;
    i32x4 pk;
    #pragma unroll
    for (int k = 0; k < 4; ++k)
        pk[k] = cvt_pk_bf16(wh_lds[gg*8 + 2*k    ][ob*16 + ar],
                            wh_lds[gg*8 + 2*k + 1][ob*16 + ar]);
    *(i32x4*)(WhF + ((b*64 + jcb)*4 + ob)*512 + ln*8) = pk;
}

// ---------------------------------------------------------------------------
// Kernel B: round-11 wave-level structure, repackaged to halve WhF L2
// traffic. 512-thread blocks (8 waves) cover 32 i-rows: wave = (j-quarter
// q = wave>>1) x (row-group rgrp = wave&1). The two waves of a quarter issue
// IDENTICAL WhF fragment loads per step (barrier-locked) -> second wave hits
// vL1, halving effective L2 fragment traffic (256MB -> ~128MB). Grid 512
// (b = bid&7 -> XCD affinity) -> 2 blocks/CU, 16 waves/CU (same as round 11).
//  - adj: global_load_lds staging, 2KB/wave/step (verified swizzle u^(r&7))
//  - Wh:  pre-fragmented global B-fragments, prefetched 1 step ahead in regs
//  - sj:  direct per-lane loads (L1-hot)
// p = exp2(max(Ci+sj, 0.2*sj+Di)) * (adj>0), fixed row max (lrelu monotone).
// ---------------------------------------------------------------------------
__global__ __launch_bounds__(512) void gat_attention(
    const int* __restrict__ adj, const unsigned short* __restrict__ WhF,
    const float* __restrict__ si2, const float* __restrict__ sj2,
    float* __restrict__ out)
{
    __shared__ char ldsbuf[33280];  // 2 x [8 wave][2KB] staging; epi 32K+512B
    const int tid  = threadIdx.x;
    const int lane = tid & 63;
    const int wave = tid >> 6;                       // 0..7
    const int q    = wave >> 1;                      // j-quarter
    const int rgrp = wave & 1;                       // row-group
    const int b    = blockIdx.x & 7;                 // batch -> XCD affinity
    const int i0   = (int)((blockIdx.x >> 3) << 5);  // 32-row i-tile
    const int arow = lane & 15;
    const int g    = lane >> 4;
    const long long bN = (long long)b * 2048;
    const int rbase = i0 + rgrp*16;                  // this wave's 16 rows

    // ---- adj staging sources (pre-swizzled: slot pu holds unit pu^(r&7)) --
    const int* asrc0;
    const int* asrc1;
    {
        int r = lane >> 3;
        int u = (lane & 7) ^ (r & 7);
        asrc0 = adj + (bN + rbase + r)*2048 + q*512 + u*4;
        int r2 = 8 + (lane >> 3);
        int u2 = (lane & 7) ^ (r2 & 7);
        asrc1 = adj + (bN + rbase + r2)*2048 + q*512 + u2*4;
    }

    // ---- B-fragment base: frag (st, ob) at fbase + (st*4 + ob)*512 ----
    //      (identical for the wave pair sharing quarter q -> vL1 dedup)
    const unsigned short* fbase =
        WhF + ((long long)(b*64 + q*16) * 4) * 512 + lane*8;

    // ---- per-batch sjmax (block-redundant, once; round-11 pattern) ----
    const float* sjb = sj2 + bN;
    float mx = -INFINITY;
    #pragma unroll 4
    for (int i = 0; i < 32; ++i) mx = fmaxf(mx, sjb[lane + i*64]);
    #pragma unroll
    for (int off = 32; off > 0; off >>= 1) mx = fmaxf(mx, __shfl_xor(mx, off));

    const float si_r = si2[bN + rbase + arow];     // P-row = arow
    const float u0f  = si_r + mx;
    const float m2   = fmaxf(u0f, ALPHA * u0f);    // fixed row max (log2 dom)
    const float Ci   = si_r - m2;
    const float Di   = ALPHA * si_r - m2;

    const float* sjq = sjb + q*512 + g*8;          // this lane's sj stream

    f32x4 accf[4];
    #pragma unroll
    for (int ob = 0; ob < 4; ++ob) accf[ob] = (f32x4){0.f,0.f,0.f,0.f};
    f32x4 accl = (f32x4){0.f,0.f,0.f,0.f};
    bf16x8 ones;
    #pragma unroll
    for (int k = 0; k < 8; ++k) ones[k] = (short)0x3F80;   // bf16 1.0

    bf16x8 cb0, cb1, cb2, cb3, nb0, nb1, nb2, nb3;

    #define STAGE(S, STEP) { \
        char* base_ = ldsbuf + (S)*16384 + wave*2048; \
        stage16(asrc0 + (STEP)*32, base_); \
        stage16(asrc1 + (STEP)*32, base_ + 1024); \
    }

    #define LOADB(D0, D1, D2, D3, STEP) { \
        D0 = *(const bf16x8*)(fbase + ((STEP)*4 + 0)*512); \
        D1 = *(const bf16x8*)(fbase + ((STEP)*4 + 1)*512); \
        D2 = *(const bf16x8*)(fbase + ((STEP)*4 + 2)*512); \
        D3 = *(const bf16x8*)(fbase + ((STEP)*4 + 3)*512); \
    }

    #define BODY(S, STEP) { \
        const char* ab = ldsbuf + (S)*16384 + wave*2048; \
        const i32x4 A0 = *(const i32x4*)(ab + arow*128 + ((g*2    ) ^ (arow & 7))*16); \
        const i32x4 A1 = *(const i32x4*)(ab + arow*128 + ((g*2 + 1) ^ (arow & 7))*16); \
        const f32x4 S0 = *(const f32x4*)(sjq + (STEP)*32); \
        const f32x4 S1 = *(const f32x4*)(sjq + (STEP)*32 + 4); \
        float p[8]; \
        _Pragma("unroll") \
        for (int e = 0; e < 4; ++e) { \
            float pe = __builtin_amdgcn_exp2f( \
                fmaxf(Ci + S0[e], fmaf(ALPHA, S0[e], Di))); \
            p[e] = (A0[e] > 0) ? pe : 0.0f; \
        } \
        _Pragma("unroll") \
        for (int e = 0; e < 4; ++e) { \
            float pe = __builtin_amdgcn_exp2f( \
                fmaxf(Ci + S1[e], fmaf(ALPHA, S1[e], Di))); \
            p[4+e] = (A1[e] > 0) ? pe : 0.0f; \
        } \
        i32x4 pk_; \
        pk_[0] = cvt_pk_bf16(p[0], p[1]); \
        pk_[1] = cvt_pk_bf16(p[2], p[3]); \
        pk_[2] = cvt_pk_bf16(p[4], p[5]); \
        pk_[3] = cvt_pk_bf16(p[6], p[7]); \
        const bf16x8 pa = __builtin_bit_cast(bf16x8, pk_); \
        accl    = __builtin_amdgcn_mfma_f32_16x16x32_bf16(pa, ones, accl,    0, 0, 0); \
        accf[0] = __builtin_amdgcn_mfma_f32_16x16x32_bf16(pa, cb0, accf[0], 0, 0, 0); \
        accf[1] = __builtin_amdgcn_mfma_f32_16x16x32_bf16(pa, cb1, accf[1], 0, 0, 0); \
        accf[2] = __builtin_amdgcn_mfma_f32_16x16x32_bf16(pa, cb2, accf[2], 0, 0, 0); \
        accf[3] = __builtin_amdgcn_mfma_f32_16x16x32_bf16(pa, cb3, accf[3], 0, 0, 0); \
    }

    // ---- prologue ----
    STAGE(0, 0);
    LOADB(cb0, cb1, cb2, cb3, 0);
    __syncthreads();

    // ---- main loop: one barrier/step; B-frags prefetched in regs ----
    int s = 0;
    for (int st = 0; st < 15; ++st) {
        STAGE(s^1, st+1);
        LOADB(nb0, nb1, nb2, nb3, st+1);
        BODY(s, st);
        __syncthreads();
        cb0 = nb0; cb1 = nb1; cb2 = nb2; cb3 = nb3;
        s ^= 1;
    }
    BODY(s, 15);

    // ---- epilogue: combine the 4 quarter partials per row, divide, store --
    __syncthreads();                          // all waves done with adj bufs
    float* accb = (float*)ldsbuf;             // [4 q][32 i][64 o] = 32KB
    float* lb   = (float*)(ldsbuf + 32768);   // [4 q][32 i] = 512B
    #pragma unroll
    for (int ob = 0; ob < 4; ++ob)
        #pragma unroll
        for (int reg = 0; reg < 4; ++reg)
            accb[(q*32 + rgrp*16 + g*4 + reg)*64 + ob*16 + arow] = accf[ob][reg];
    if (arow == 0) {
        #pragma unroll
        for (int reg = 0; reg < 4; ++reg)
            lb[q*32 + rgrp*16 + g*4 + reg] = accl[reg];
    }
    __syncthreads();

    const int r  = tid >> 4;                  // 0..31
    const int c0 = (tid & 15) * 4;
    const float L = lb[r] + lb[32 + r] + lb[64 + r] + lb[96 + r];
    const float inv = 1.0f / L;
    float4 v;
    v.x = (accb[r*64 + c0 + 0] + accb[(32+r)*64 + c0 + 0]
         + accb[(64+r)*64 + c0 + 0] + accb[(96+r)*64 + c0 + 0]) * inv;
    v.y = (accb[r*64 + c0 + 1] + accb[(32+r)*64 + c0 + 1]
         + accb[(64+r)*64 + c0 + 1] + accb[(96+r)*64 + c0 + 1]) * inv;
    v.z = (accb[r*64 + c0 + 2] + accb[(32+r)*64 + c0 + 2]
         + accb[(64+r)*64 + c0 + 2] + accb[(96+r)*64 + c0 + 2]) * inv;
    v.w = (accb[r*64 + c0 + 3] + accb[(32+r)*64 + c0 + 3]
         + accb[(64+r)*64 + c0 + 3] + accb[(96+r)*64 + c0 + 3]) * inv;
    *(float4*)(out + (bN + i0 + r)*64 + c0) = v;
}

// ---------------------------------------------------------------------------
// ws layout: WhF 2MB | si2 64KB | sj2 64KB
// ---------------------------------------------------------------------------
extern "C" void kernel_launch(void* const* d_in, const int* in_sizes, int n_in,
                              void* d_out, int out_size, void* d_ws, size_t ws_size,
                              hipStream_t stream) {
    const float* h   = (const float*)d_in[0];
    const int*   adj = (const int*)d_in[1];
    const float* W   = (const float*)d_in[2];
    const float* a   = (const float*)d_in[3];
    float* out = (float*)d_out;

    unsigned short* WhF = (unsigned short*)d_ws;                // 2 MB
    float* si2 = (float*)((char*)d_ws + (size_t)16384*64*2);
    float* sj2 = si2 + 16384;

    gat_precompute<<<512, 256, 0, stream>>>(h, W, a, WhF, si2, sj2);
    gat_attention<<<512, 512, 0, stream>>>(adj, WhF, si2, sj2, out);
}

// Round 17
// 45.015 us; speedup vs baseline: 1.4666x; 1.0023x over previous
//
#include <hip/hip_runtime.h>
#include <hip/hip_bf16.h>

#define ALPHA 0.2f
#define LOG2E 1.4426950408889634f

typedef __attribute__((ext_vector_type(8))) short bf16x8;
typedef __attribute__((ext_vector_type(4))) float f32x4;
typedef __attribute__((ext_vector_type(4))) int i32x4;

__device__ __forceinline__ int cvt_pk_bf16(float lo, float hi) {
    int r;
    asm("v_cvt_pk_bf16_f32 %0, %1, %2" : "=v"(r) : "v"(lo), "v"(hi));
    return r;
}

// async global->LDS, 16B per lane; LDS dest = wave-uniform base + lane*16
__device__ __forceinline__ void stage16(const void* g, void* l) {
    __builtin_amdgcn_global_load_lds(
        (const __attribute__((address_space(1))) void*)g,
        (__attribute__((address_space(3))) void*)l, 16, 0, 0);
}

// ---------------------------------------------------------------------------
// Kernel A (verified): Wh = h @ W (fp32), si2/sj2 scaled by log2e, Wh emitted
// PRE-FRAGMENTED for the MFMA B operand:
//   WhF[((b*64 + jc)*4 + ob)*512 + lane*8 + e] = bf16(Wh[j][o]),
//   j = jc*32 + (lane>>4)*8 + e, o = ob*16 + (lane&15)
// ---------------------------------------------------------------------------
__global__ __launch_bounds__(256) void gat_precompute(
    const float* __restrict__ h, const float* __restrict__ W,
    const float* __restrict__ a, unsigned short* __restrict__ WhF,
    float* __restrict__ si2, float* __restrict__ sj2)
{
    __shared__ float h_lds[32][128];
    __shared__ float wh_lds[32][65];   // +1 pad
    const int tid  = threadIdx.x;
    const int lane = tid & 63;
    const int wave = tid >> 6;
    const long long row0 = (long long)blockIdx.x * 32;

    {
        const float4* s4 = (const float4*)(h + row0 * 128);
        #pragma unroll
        for (int i = 0; i < 4; ++i) {
            int idx = tid + i * 256;
            float4 v = s4[idx];
            *(float4*)&h_lds[idx >> 5][(idx & 31) * 4] = v;
        }
    }
    __syncthreads();

    const float a1 = a[lane];
    const float a2 = a[64 + lane];
    float acc[8];
    #pragma unroll
    for (int r = 0; r < 8; ++r) acc[r] = 0.0f;

    for (int f = 0; f < 128; f += 4) {
        const float w0 = W[(f+0)*64 + lane];
        const float w1 = W[(f+1)*64 + lane];
        const float w2 = W[(f+2)*64 + lane];
        const float w3 = W[(f+3)*64 + lane];
        #pragma unroll
        for (int r = 0; r < 8; ++r) {
            const float4 hv = *(const float4*)&h_lds[wave*8 + r][f];
            acc[r] = fmaf(hv.x, w0, acc[r]);
            acc[r] = fmaf(hv.y, w1, acc[r]);
            acc[r] = fmaf(hv.z, w2, acc[r]);
            acc[r] = fmaf(hv.w, w3, acc[r]);
        }
    }

    #pragma unroll
    for (int r = 0; r < 8; ++r) {
        const int rr = wave*8 + r;
        wh_lds[rr][lane] = acc[r];
        float s1 = acc[r] * a1;
        float s2 = acc[r] * a2;
        #pragma unroll
        for (int off = 32; off > 0; off >>= 1) {
            s1 += __shfl_xor(s1, off);
            s2 += __shfl_xor(s2, off);
        }
        if (lane == 0) {
            si2[row0 + rr] = s1 * LOG2E;
            sj2[row0 + rr] = s2 * LOG2E;
        }
    }
    __syncthreads();

    // fragment write: tid = ob*64 + lane
    const long long b  = row0 >> 11;
    const int jcb  = (int)((row0 & 2047) >> 5);   // j-chunk within batch
    const int ob   = tid >> 6;
    const int ln   = tid & 63;
    const int ar   = ln & 15;
    const int gg   = ln >> 4;
    i32x4 pk;
    #pragma unroll
    for (int k = 0; k < 4; ++k)
        pk[k] = cvt_pk_bf16(wh_lds[gg*8 + 2*k    ][ob*16 + ar],
                            wh_lds[gg*8 + 2*k + 1][ob*16 + ar]);
    *(i32x4*)(WhF + ((b*64 + jcb)*4 + ob)*512 + ln*8) = pk;
}

// ---------------------------------------------------------------------------
// Kernel B (round-15 best, 45.1us): round-11 wave-level structure, 512-thread
// blocks (8 waves) cover 32 i-rows: wave = (j-quarter q) x (row-group rgrp).
// The two waves of a quarter issue IDENTICAL WhF fragment loads per step
// (barrier-locked) -> vL1 dedup. Grid 512 (b = bid&7 -> XCD affinity).
//  - adj: global_load_lds staging, 2KB/wave/step (verified swizzle u^(r&7))
//  - Wh:  pre-fragmented global B-fragments, prefetched 1 step ahead in regs
//  - sj:  direct per-lane loads (L1-hot)
// p = exp2(max(Ci+sj, 0.2*sj+Di)) * (adj>0), fixed row max (lrelu monotone).
// ---------------------------------------------------------------------------
__global__ __launch_bounds__(512) void gat_attention(
    const int* __restrict__ adj, const unsigned short* __restrict__ WhF,
    const float* __restrict__ si2, const float* __restrict__ sj2,
    float* __restrict__ out)
{
    __shared__ char ldsbuf[33280];  // 2 x [8 wave][2KB] staging; epi 32K+512B
    const int tid  = threadIdx.x;
    const int lane = tid & 63;
    const int wave = tid >> 6;                       // 0..7
    const int q    = wave >> 1;                      // j-quarter
    const int rgrp = wave & 1;                       // row-group
    const int b    = blockIdx.x & 7;                 // batch -> XCD affinity
    const int i0   = (int)((blockIdx.x >> 3) << 5);  // 32-row i-tile
    const int arow = lane & 15;
    const int g    = lane >> 4;
    const long long bN = (long long)b * 2048;
    const int rbase = i0 + rgrp*16;                  // this wave's 16 rows

    // ---- adj staging sources (pre-swizzled: slot pu holds unit pu^(r&7)) --
    const int* asrc0;
    const int* asrc1;
    {
        int r = lane >> 3;
        int u = (lane & 7) ^ (r & 7);
        asrc0 = adj + (bN + rbase + r)*2048 + q*512 + u*4;
        int r2 = 8 + (lane >> 3);
        int u2 = (lane & 7) ^ (r2 & 7);
        asrc1 = adj + (bN + rbase + r2)*2048 + q*512 + u2*4;
    }

    // ---- B-fragment base: frag (st, ob) at fbase + (st*4 + ob)*512 ----
    //      (identical for the wave pair sharing quarter q -> vL1 dedup)
    const unsigned short* fbase =
        WhF + ((long long)(b*64 + q*16) * 4) * 512 + lane*8;

    // ---- per-batch sjmax (block-redundant, once) ----
    const float* sjb = sj2 + bN;
    float mx = -INFINITY;
    #pragma unroll 4
    for (int i = 0; i < 32; ++i) mx = fmaxf(mx, sjb[lane + i*64]);
    #pragma unroll
    for (int off = 32; off > 0; off >>= 1) mx = fmaxf(mx, __shfl_xor(mx, off));

    const float si_r = si2[bN + rbase + arow];     // P-row = arow
    const float u0f  = si_r + mx;
    const float m2   = fmaxf(u0f, ALPHA * u0f);    // fixed row max (log2 dom)
    const float Ci   = si_r - m2;
    const float Di   = ALPHA * si_r - m2;

    const float* sjq = sjb + q*512 + g*8;          // this lane's sj stream

    f32x4 accf[4];
    #pragma unroll
    for (int ob = 0; ob < 4; ++ob) accf[ob] = (f32x4){0.f,0.f,0.f,0.f};
    f32x4 accl = (f32x4){0.f,0.f,0.f,0.f};
    bf16x8 ones;
    #pragma unroll
    for (int k = 0; k < 8; ++k) ones[k] = (short)0x3F80;   // bf16 1.0

    bf16x8 cb0, cb1, cb2, cb3, nb0, nb1, nb2, nb3;

    #define STAGE(S, STEP) { \
        char* base_ = ldsbuf + (S)*16384 + wave*2048; \
        stage16(asrc0 + (STEP)*32, base_); \
        stage16(asrc1 + (STEP)*32, base_ + 1024); \
    }

    #define LOADB(D0, D1, D2, D3, STEP) { \
        D0 = *(const bf16x8*)(fbase + ((STEP)*4 + 0)*512); \
        D1 = *(const bf16x8*)(fbase + ((STEP)*4 + 1)*512); \
        D2 = *(const bf16x8*)(fbase + ((STEP)*4 + 2)*512); \
        D3 = *(const bf16x8*)(fbase + ((STEP)*4 + 3)*512); \
    }

    #define BODY(S, STEP) { \
        const char* ab = ldsbuf + (S)*16384 + wave*2048; \
        const i32x4 A0 = *(const i32x4*)(ab + arow*128 + ((g*2    ) ^ (arow & 7))*16); \
        const i32x4 A1 = *(const i32x4*)(ab + arow*128 + ((g*2 + 1) ^ (arow & 7))*16); \
        const f32x4 S0 = *(const f32x4*)(sjq + (STEP)*32); \
        const f32x4 S1 = *(const f32x4*)(sjq + (STEP)*32 + 4); \
        float p[8]; \
        _Pragma("unroll") \
        for (int e = 0; e < 4; ++e) { \
            float pe = __builtin_amdgcn_exp2f( \
                fmaxf(Ci + S0[e], fmaf(ALPHA, S0[e], Di))); \
            p[e] = (A0[e] > 0) ? pe : 0.0f; \
        } \
        _Pragma("unroll") \
        for (int e = 0; e < 4; ++e) { \
            float pe = __builtin_amdgcn_exp2f( \
                fmaxf(Ci + S1[e], fmaf(ALPHA, S1[e], Di))); \
            p[4+e] = (A1[e] > 0) ? pe : 0.0f; \
        } \
        i32x4 pk_; \
        pk_[0] = cvt_pk_bf16(p[0], p[1]); \
        pk_[1] = cvt_pk_bf16(p[2], p[3]); \
        pk_[2] = cvt_pk_bf16(p[4], p[5]); \
        pk_[3] = cvt_pk_bf16(p[6], p[7]); \
        const bf16x8 pa = __builtin_bit_cast(bf16x8, pk_); \
        accl    = __builtin_amdgcn_mfma_f32_16x16x32_bf16(pa, ones, accl,    0, 0, 0); \
        accf[0] = __builtin_amdgcn_mfma_f32_16x16x32_bf16(pa, cb0, accf[0], 0, 0, 0); \
        accf[1] = __builtin_amdgcn_mfma_f32_16x16x32_bf16(pa, cb1, accf[1], 0, 0, 0); \
        accf[2] = __builtin_amdgcn_mfma_f32_16x16x32_bf16(pa, cb2, accf[2], 0, 0, 0); \
        accf[3] = __builtin_amdgcn_mfma_f32_16x16x32_bf16(pa, cb3, accf[3], 0, 0, 0); \
    }

    // ---- prologue ----
    STAGE(0, 0);
    LOADB(cb0, cb1, cb2, cb3, 0);
    __syncthreads();

    // ---- main loop: one barrier/step; B-frags prefetched in regs ----
    int s = 0;
    for (int st = 0; st < 15; ++st) {
        STAGE(s^1, st+1);
        LOADB(nb0, nb1, nb2, nb3, st+1);
        BODY(s, st);
        __syncthreads();
        cb0 = nb0; cb1 = nb1; cb2 = nb2; cb3 = nb3;
        s ^= 1;
    }
    BODY(s, 15);

    // ---- epilogue: combine the 4 quarter partials per row, divide, store --
    __syncthreads();                          // all waves done with adj bufs
    float* accb = (float*)ldsbuf;             // [4 q][32 i][64 o] = 32KB
    float* lb   = (float*)(ldsbuf + 32768);   // [4 q][32 i] = 512B
    #pragma unroll
    for (int ob = 0; ob < 4; ++ob)
        #pragma unroll
        for (int reg = 0; reg < 4; ++reg)
            accb[(q*32 + rgrp*16 + g*4 + reg)*64 + ob*16 + arow] = accf[ob][reg];
    if (arow == 0) {
        #pragma unroll
        for (int reg = 0; reg < 4; ++reg)
            lb[q*32 + rgrp*16 + g*4 + reg] = accl[reg];
    }
    __syncthreads();

    const int r  = tid >> 4;                  // 0..31
    const int c0 = (tid & 15) * 4;
    const float L = lb[r] + lb[32 + r] + lb[64 + r] + lb[96 + r];
    const float inv = 1.0f / L;
    float4 v;
    v.x = (accb[r*64 + c0 + 0] + accb[(32+r)*64 + c0 + 0]
         + accb[(64+r)*64 + c0 + 0] + accb[(96+r)*64 + c0 + 0]) * inv;
    v.y = (accb[r*64 + c0 + 1] + accb[(32+r)*64 + c0 + 1]
         + accb[(64+r)*64 + c0 + 1] + accb[(96+r)*64 + c0 + 1]) * inv;
    v.z = (accb[r*64 + c0 + 2] + accb[(32+r)*64 + c0 + 2]
         + accb[(64+r)*64 + c0 + 2] + accb[(96+r)*64 + c0 + 2]) * inv;
    v.w = (accb[r*64 + c0 + 3] + accb[(32+r)*64 + c0 + 3]
         + accb[(64+r)*64 + c0 + 3] + accb[(96+r)*64 + c0 + 3]) * inv;
    *(float4*)(out + (bN + i0 + r)*64 + c0) = v;
}

// ---------------------------------------------------------------------------
// ws layout: WhF 2MB | si2 64KB | sj2 64KB
// ---------------------------------------------------------------------------
extern "C" void kernel_launch(void* const* d_in, const int* in_sizes, int n_in,
                              void* d_out, int out_size, void* d_ws, size_t ws_size,
                              hipStream_t stream) {
    const float* h   = (const float*)d_in[0];
    const int*   adj = (const int*)d_in[1];
    const float* W   = (const float*)d_in[2];
    const float* a   = (const float*)d_in[3];
    float* out = (float*)d_out;

    unsigned short* WhF = (unsigned short*)d_ws;                // 2 MB
    float* si2 = (float*)((char*)d_ws + (size_t)16384*64*2);
    float* sj2 = si2 + 16384;

    gat_precompute<<<512, 256, 0, stream>>>(h, W, a, WhF, si2, sj2);
    gat_attention<<<512, 512, 0, stream>>>(adj, WhF, si2, sj2, out);
}